// Round 4
// baseline (335.783 us; speedup 1.0000x reference)
//
#include <hip/hip_runtime.h>
#include <hip/hip_bf16.h>

// CTC greedy search:  logits (T,N,V) fp32, in_lens (N) int32.
// Outputs (all fp32, concatenated): max_total (N), paths (T,N), out_lens (N).
//
// Structure:
//  K1: one wave per (t,n) row -> -log(sum exp(x-max)) into rmaxT[n*T+t]
//      (transposed, for K2's coalesced sum reads) and argmax into
//      out_paths[t*N+n] (natural order == the default/"undefined-region"
//      value masked_scatter_ leaves behind; also K2's argmax source).
//  K2: one block per n: dedup+mask -> block scan -> scatter kept tokens
//      over the compacted prefix of out_paths (register-stashed, 1 pass).

#define WAVE 64

typedef float nvec4 __attribute__((ext_vector_type(4)));

// ---------------- Kernel 1: per-(t,n) row logsumexp-max + argmax -------------
template <int CH>
__global__ __launch_bounds__(256) void row_lse_kernel(
    const float* __restrict__ logits,
    float* __restrict__ rmaxT, float* __restrict__ out_paths,
    int T, int N, int rows) {
  const int lane = threadIdx.x & (WAVE - 1);
  const int w    = threadIdx.x >> 6;            // wave id in block (0..3)
  const int row  = blockIdx.x * 4 + w;
  const bool active = row < rows;
  const int V = CH * 256;
  const nvec4* p4 = (const nvec4*)(logits + (size_t)(active ? row : 0) * V);

  float m = -3.4e38f;
  int   mi = 0;
  nvec4 v[CH];
#pragma unroll
  for (int c = 0; c < CH; ++c) {
    // streamed exactly once -> nontemporal, keep L2 for the intermediates
    v[c] = __builtin_nontemporal_load(p4 + c * 64 + lane);
    const int idx = c * 256 + lane * 4;
    if (v[c].x > m) { m = v[c].x; mi = idx; }
    if (v[c].y > m) { m = v[c].y; mi = idx + 1; }
    if (v[c].z > m) { m = v[c].z; mi = idx + 2; }
    if (v[c].w > m) { m = v[c].w; mi = idx + 3; }
  }
  // wave reduce: max value, first (lowest) index on ties
#pragma unroll
  for (int off = 32; off; off >>= 1) {
    const float om = __shfl_down(m, off);
    const int   oi = __shfl_down(mi, off);
    if (om > m || (om == m && oi < mi)) { m = om; mi = oi; }
  }
  m = __shfl(m, 0);  // broadcast row max

  float s = 0.f;
#pragma unroll
  for (int c = 0; c < CH; ++c)
    s += __expf(v[c].x - m) + __expf(v[c].y - m) +
         __expf(v[c].z - m) + __expf(v[c].w - m);
#pragma unroll
  for (int off = 32; off; off >>= 1) s += __shfl_down(s, off);

  __shared__ int s_arg[4];
  if (lane == 0 && active) {
    const int t = row / N, n = row % N;
    // max(log_softmax) = max - lse = -log(sum exp(x - max))
    rmaxT[(size_t)n * T + t] = -__logf(s);
    s_arg[w] = mi;
  }
  __syncthreads();
  if (threadIdx.x < 4) {
    const int r = blockIdx.x * 4 + threadIdx.x;
    if (r < rows) out_paths[r] = (float)s_arg[threadIdx.x];  // coalesced
  }
}

// Generic fallback (any V): strided row scan.
__global__ __launch_bounds__(256) void row_lse_generic(
    const float* __restrict__ logits,
    float* __restrict__ rmaxT, float* __restrict__ out_paths,
    int T, int N, int V, int rows) {
  const int lane = threadIdx.x & (WAVE - 1);
  const int w    = threadIdx.x >> 6;
  const int row  = blockIdx.x * 4 + w;
  const bool active = row < rows;
  const float* p = logits + (size_t)(active ? row : 0) * V;

  float m = -3.4e38f; int mi = 0;
  for (int i = lane; i < V; i += WAVE) {
    const float x = p[i];
    if (x > m) { m = x; mi = i; }
  }
  for (int off = 32; off; off >>= 1) {
    const float om = __shfl_down(m, off);
    const int   oi = __shfl_down(mi, off);
    if (om > m || (om == m && oi < mi)) { m = om; mi = oi; }
  }
  m = __shfl(m, 0);
  float s = 0.f;
  for (int i = lane; i < V; i += WAVE) s += __expf(p[i] - m);
  for (int off = 32; off; off >>= 1) s += __shfl_down(s, off);

  __shared__ int s_arg[4];
  if (lane == 0 && active) {
    const int t = row / N, n = row % N;
    rmaxT[(size_t)n * T + t] = -__logf(s);
    s_arg[w] = mi;
  }
  __syncthreads();
  if (threadIdx.x < 4) {
    const int r = blockIdx.x * 4 + threadIdx.x;
    if (r < rows) out_paths[r] = (float)s_arg[threadIdx.x];
  }
}

// ---------------- Kernel 2: per-n dedup + compaction + sums ------------------
// Reads argmax from out_paths (written by K1), stashes kept tokens in
// registers (single pass), scans, scatters. Blocks touch disjoint columns n,
// so the read-then-overwrite of out_paths is safe (scan barriers order the
// block-internal phases; stream order covers K1->K2).
#define CB 256
template <int ITEMS>
__global__ __launch_bounds__(CB) void ctc_compact_kernel(
    const float* __restrict__ rmaxT, const int* __restrict__ in_lens,
    float* __restrict__ out, int T, int N, int V) {
  const int n = blockIdx.x;
  const int tid = threadIdx.x;
  const int L = in_lens[n];
  const int blank = V - 1;            // (-1 + V) % V
  const int t0 = tid * ITEMS;

  float* out_total = out;
  float* out_paths = out + N;                    // (T, N) layout
  float* out_lens  = out + N + (size_t)T * N;

  const float* rm = rmaxT + (size_t)n * T;

  int   cnt = 0;
  float sum = 0.f;
  int   keepa[ITEMS];
  int prev = (t0 > 0 && t0 <= T) ? (int)out_paths[(size_t)(t0 - 1) * N + n] : -1;
#pragma unroll
  for (int i = 0; i < ITEMS; ++i) {
    const int t = t0 + i;
    if (t >= T) break;
    const int a = (int)out_paths[(size_t)t * N + n];
    const bool keep = (t < L) && (a != blank) && (t == 0 || a != prev);
    prev = a;
    if (t < L) sum += rm[t];                     // coalesced (transposed layout)
    if (keep) keepa[cnt++] = a;
  }

  __shared__ int   s_cnt[CB];
  __shared__ float s_sum[CB];
  s_cnt[tid] = cnt;
  s_sum[tid] = sum;
  __syncthreads();
  // inclusive Hillis-Steele scan (cnt); sum rides along as a reduction
  for (int off = 1; off < CB; off <<= 1) {
    const int   c  = (tid >= off) ? s_cnt[tid - off] : 0;
    const float sv = (tid >= off) ? s_sum[tid - off] : 0.f;
    __syncthreads();
    s_cnt[tid] += c;
    s_sum[tid] += sv;
    __syncthreads();
  }
  const int prefix = s_cnt[tid] - cnt;           // exclusive
  if (tid == 0) {
    out_total[n] = s_sum[CB - 1];
    out_lens[n]  = (float)s_cnt[CB - 1];
  }

  // scatter kept tokens into the compacted prefix (masked_scatter_ semantics:
  // slots >= out_lens keep the K1 defaults = raw argmax)
  for (int k = 0; k < cnt; ++k)
    out_paths[(size_t)(prefix + k) * N + n] = (float)keepa[k];
}

// Fallback for shapes where T > CB*16: two-pass variant (no register stash).
__global__ __launch_bounds__(CB) void ctc_compact_generic(
    const float* __restrict__ rmaxT, const int* __restrict__ in_lens,
    float* __restrict__ out, int T, int N, int V) {
  const int n = blockIdx.x;
  const int tid = threadIdx.x;
  const int L = in_lens[n];
  const int blank = V - 1;
  const int items = (T + CB - 1) / CB;
  const int t0 = tid * items;

  float* out_total = out;
  float* out_paths = out + N;
  float* out_lens  = out + N + (size_t)T * N;
  const float* rm = rmaxT + (size_t)n * T;

  int cnt = 0; float sum = 0.f;
  int prev = (t0 > 0 && t0 <= T) ? (int)out_paths[(size_t)(t0 - 1) * N + n] : -1;
  for (int i = 0; i < items; ++i) {
    const int t = t0 + i;
    if (t >= T) break;
    const int a = (int)out_paths[(size_t)t * N + n];
    const bool keep = (t < L) && (a != blank) && (t == 0 || a != prev);
    prev = a;
    cnt += keep ? 1 : 0;
    if (t < L) sum += rm[t];
  }

  __shared__ int   s_cnt[CB];
  __shared__ float s_sum[CB];
  __shared__ int   s_a[CB];   // unused, keeps layout simple
  (void)s_a;
  s_cnt[tid] = cnt; s_sum[tid] = sum;
  __syncthreads();
  for (int off = 1; off < CB; off <<= 1) {
    const int   c  = (tid >= off) ? s_cnt[tid - off] : 0;
    const float sv = (tid >= off) ? s_sum[tid - off] : 0.f;
    __syncthreads();
    s_cnt[tid] += c; s_sum[tid] += sv;
    __syncthreads();
  }
  const int prefix = s_cnt[tid] - cnt;
  if (tid == 0) { out_total[n] = s_sum[CB - 1]; out_lens[n] = (float)s_cnt[CB - 1]; }

  // must re-read BEFORE overwriting: stage this thread's values first
  int vals[32];  // items <= 32 supported here (T <= 8192)
  int kc = 0;
  prev = (t0 > 0 && t0 <= T) ? (int)out_paths[(size_t)(t0 - 1) * N + n] : -1;
  for (int i = 0; i < items && i < 32; ++i) {
    const int t = t0 + i;
    if (t >= T) break;
    const int a = (int)out_paths[(size_t)t * N + n];
    const bool keep = (t < L) && (a != blank) && (t == 0 || a != prev);
    prev = a;
    if (keep) vals[kc++] = a;
  }
  __syncthreads();   // all re-reads done before any overwrite
  for (int k = 0; k < kc; ++k)
    out_paths[(size_t)(prefix + k) * N + n] = (float)vals[k];
}

extern "C" void kernel_launch(void* const* d_in, const int* in_sizes, int n_in,
                              void* d_out, int out_size, void* d_ws, size_t ws_size,
                              hipStream_t stream) {
  const float* logits = (const float*)d_in[0];
  const int* in_lens  = (const int*)d_in[1];
  float* out = (float*)d_out;

  const int N = in_sizes[1];
  const int T = (out_size - 2 * N) / N;          // out = N + T*N + N
  const long long total = in_sizes[0];
  const int V = (int)(total / ((long long)T * N));
  const int rows = T * N;

  float* rmaxT = (float*)d_ws;                   // T*N floats
  float* out_paths = out + N;

  const int grid1 = (rows + 3) / 4;              // 4 waves (rows) per block

  if (V == 1024) {
    row_lse_kernel<4><<<grid1, 256, 0, stream>>>(logits, rmaxT, out_paths, T, N, rows);
  } else if (V == 512) {
    row_lse_kernel<2><<<grid1, 256, 0, stream>>>(logits, rmaxT, out_paths, T, N, rows);
  } else if (V == 2048) {
    row_lse_kernel<8><<<grid1, 256, 0, stream>>>(logits, rmaxT, out_paths, T, N, rows);
  } else {
    row_lse_generic<<<grid1, 256, 0, stream>>>(logits, rmaxT, out_paths, T, N, V, rows);
  }

  if (T <= CB * 8) {
    ctc_compact_kernel<8><<<N, CB, 0, stream>>>(rmaxT, in_lens, out, T, N, V);
  } else if (T <= CB * 16) {
    ctc_compact_kernel<16><<<N, CB, 0, stream>>>(rmaxT, in_lens, out, T, N, V);
  } else {
    ctc_compact_generic<<<N, CB, 0, stream>>>(rmaxT, in_lens, out, T, N, V);
  }
}